// Round 4
// baseline (230.117 us; speedup 1.0000x reference)
//
#include <hip/hip_runtime.h>
#include <hip/hip_bf16.h>

// Problem constants (fixed by the reference: B=4,S=2048,D=1024,E=8,H=1024)
#define T_TOK 8192
#define DDIM  1024
#define NEXP  8
#define HDIM  1024
#define SLOT_CAP 18432   // 72 M-tiles * 256; >= 16384 + 8*255 padding worst case
#define NCBLK 32         // blocks for count/slotfill

typedef short bf16x8 __attribute__((ext_vector_type(8)));   // 8 bf16 in 4 VGPRs
typedef float f32x4  __attribute__((ext_vector_type(4)));
typedef unsigned short u16x8 __attribute__((ext_vector_type(8)));

typedef const __attribute__((address_space(1))) unsigned int* gas_ptr;
typedef __attribute__((address_space(3))) unsigned int*       las_ptr;
#define GLD16(gp, lp) __builtin_amdgcn_global_load_lds((gas_ptr)(gp), (las_ptr)(lp), 16, 0, 0)

// fp32 -> bf16 round-to-nearest-even
static __device__ __forceinline__ unsigned short f2b(float f) {
    union { float f; unsigned int u; } v; v.f = f;
    unsigned int u = v.u;
    u += 0x7fffu + ((u >> 16) & 1u);
    return (unsigned short)(u >> 16);
}
static __device__ __forceinline__ float b2f(unsigned short h) {
    union { unsigned int u; float f; } v; v.u = ((unsigned int)h) << 16;
    return v.f;
}

// ---------------------------------------------------------------------------
// K1: routing, one WAVE per token (4 tokens/block, no LDS, no barriers).
// fp64 logits (selection-exact), shfl_xor butterfly, fused x->bf16.
// ---------------------------------------------------------------------------
__global__ __launch_bounds__(256) void moe_routing(
    const float* __restrict__ x, const float* __restrict__ wg,
    unsigned short* __restrict__ xb,
    int* __restrict__ tok_e, float* __restrict__ tok_g)
{
    int wv   = threadIdx.x >> 6;        // wave 0..3 -> token
    int lane = threadIdx.x & 63;
    int t    = blockIdx.x * 4 + wv;

    const float4* xr = (const float4*)(x + (size_t)t * DDIM);
    float4 v[4];
    #pragma unroll
    for (int i = 0; i < 4; i++) v[i] = xr[lane + 64 * i];

    ushort4* xw = (ushort4*)(xb + (size_t)t * DDIM);
    #pragma unroll
    for (int i = 0; i < 4; i++) {
        ushort4 s4;
        s4.x = f2b(v[i].x); s4.y = f2b(v[i].y);
        s4.z = f2b(v[i].z); s4.w = f2b(v[i].w);
        xw[lane + 64 * i] = s4;
    }

    double s[NEXP];
    #pragma unroll
    for (int e = 0; e < NEXP; e++) s[e] = 0.0;
    #pragma unroll
    for (int i = 0; i < 4; i++) {
        const float* wr = wg + ((size_t)lane * 4 + 256 * i) * NEXP;
        #pragma unroll
        for (int j = 0; j < 4; j++) {
            double xj = (double)((&v[i].x)[j]);
            #pragma unroll
            for (int e = 0; e < NEXP; e++)
                s[e] += xj * (double)wr[j * NEXP + e];
        }
    }

    #pragma unroll
    for (int off = 32; off > 0; off >>= 1) {
        #pragma unroll
        for (int e = 0; e < NEXP; e++)
            s[e] += __shfl_xor(s[e], off, 64);
    }

    if (lane == 0) {
        int e0 = 0;
        for (int e = 1; e < NEXP; e++) if (s[e] > s[e0]) e0 = e;
        int e1 = (e0 == 0) ? 1 : 0;
        for (int e = 0; e < NEXP; e++) if (e != e0 && s[e] > s[e1]) e1 = e;
        double g0 = 1.0 / (1.0 + exp(s[e1] - s[e0]));
        tok_e[2*t] = e0; tok_e[2*t+1] = e1;
        tok_g[2*t] = (float)g0; tok_g[2*t+1] = (float)(1.0 - g0);
    }
}

// ---------------------------------------------------------------------------
// K2a: per-block expert histogram -> cnt_part[b][e].
// ---------------------------------------------------------------------------
__global__ __launch_bounds__(256) void moe_count(
    const int* __restrict__ tok_e, int* __restrict__ cnt_part)
{
    __shared__ int h[NEXP];
    if (threadIdx.x < NEXP) h[threadIdx.x] = 0;
    __syncthreads();
    int t = blockIdx.x * 256 + threadIdx.x;
    atomicAdd(&h[tok_e[2*t]], 1);
    atomicAdd(&h[tok_e[2*t+1]], 1);
    __syncthreads();
    if (threadIdx.x < NEXP)
        cnt_part[blockIdx.x * NEXP + threadIdx.x] = h[threadIdx.x];
}

// ---------------------------------------------------------------------------
// K2b: redundant reduce of cnt_part per block -> counts + 256-ALIGNED meta
// (R10: gemm M-tile is now 256) + deterministic cross-block bases. Block 0
// publishes meta/counts. prefix+rank is unique per slot.
// ---------------------------------------------------------------------------
__global__ __launch_bounds__(256) void moe_slotfill(
    const int* __restrict__ tok_e, const int* __restrict__ cnt_part,
    int* __restrict__ meta, int* __restrict__ counts,
    int* __restrict__ slot_token, int* __restrict__ tok_slot)
{
    __shared__ int h[NEXP];
    __shared__ int tots[NEXP], pres[NEXP], base[NEXP];
    int tid = threadIdx.x;
    if (tid < NEXP) h[tid] = 0;
    __syncthreads();
    int t = blockIdx.x * 256 + tid;
    int e0 = tok_e[2*t],     e1 = tok_e[2*t + 1];
    int r0 = atomicAdd(&h[e0], 1);
    int r1 = atomicAdd(&h[e1], 1);
    if (tid < NEXP) {
        int pre = 0, tot = 0;
        for (int b = 0; b < NCBLK; b++) {
            int c = cnt_part[b * NEXP + tid];
            if (b < (int)blockIdx.x) pre += c;
            tot += c;
        }
        tots[tid] = tot; pres[tid] = pre;
    }
    __syncthreads();
    if (tid < NEXP) {
        int off = 0;
        for (int e = 0; e < tid; e++) off += (tots[e] + 255) & ~255;
        base[tid] = off + pres[tid];
        if (blockIdx.x == 0) {
            meta[tid]   = off;
            counts[tid] = tots[tid];
            if (tid == NEXP - 1) meta[NEXP] = off + ((tots[tid] + 255) & ~255);
        }
    }
    __syncthreads();
    int s0 = base[e0] + r0, s1 = base[e1] + r1;
    slot_token[s0] = t;  tok_slot[2*t]     = s0;
    slot_token[s1] = t;  tok_slot[2*t + 1] = s1;
}

// K3: We [E][D][H] fp32 -> Wt [E][H][D] bf16 (transpose for GEMM B loads).
__global__ __launch_bounds__(256) void moe_wtrans(
    const float* __restrict__ we, unsigned short* __restrict__ wt)
{
    __shared__ unsigned short tile[64][65];
    int e  = blockIdx.z;
    int d0 = blockIdx.y * 64;
    int h0 = blockIdx.x * 64;
    int c  = threadIdx.x & 63;
    int r4 = threadIdx.x >> 6;
    #pragma unroll
    for (int i = 0; i < 64; i += 4)
        tile[r4 + i][c] = f2b(we[((size_t)e * DDIM + d0 + r4 + i) * HDIM + h0 + c]);
    __syncthreads();
    #pragma unroll
    for (int i = 0; i < 64; i += 4)
        wt[((size_t)e * HDIM + h0 + r4 + i) * DDIM + d0 + c] = tile[c][r4 + i];
}

// ---------------------------------------------------------------------------
// K4 (R10 rewrite): 256x256-tile phase-interleaved grouped gather-GEMM.
// R8's 2-phase 128^2 hit the measured 2-phase grouped ceiling (537 TF ~=
// 655 TF * 1.43-round tail). This is the T3+T4 schedule (m248: 848 TF
// grouped @K=1024) in plain HIP:
//   - 512 thr / 8 waves (2M x 4N, each owns 128x64 C), BK=32, K-tiles=32
//   - LDS ring of 4 K-tile buffers (A 16KB + B 16KB each) = 128 KB, 1 blk/CU
//   - stage lead 2 tiles: during tile t, phase0 stages A(t+2), phase1 B(t+2)
//     (2 GLD16/thread each). Dest buf (t+2)&3 was last READ at tile t-2,
//     >=4 barriers ago -> WAR-safe.
//   - ONE counted wait per tile, at the boundary: younger-than-tile-(t+1)
//     loads are exactly tile (t+2)'s 4 -> vmcnt(4) steady; vmcnt(0) only at
//     t=30 (drains tile 31). wait-BEFORE-barrier makes it collective.
//   - per phase: {ds_read_b128 x8|x4 || 2 GLD16 -> barrier -> setprio(1),
//     16 MFMA, setprio(0) -> barrier} (T5 pays only in this regime, m218b).
//   - ds:MFMA = 12:32 per tile/wave = same ratio as the verified template.
// Swizzle pair (source col ^ (row>>1)&3, reader quad^ff) carried unchanged.
// Grid 72x4=288 (%8==0); XCD remap: 4 consecutive wid share one A-panel.
// ---------------------------------------------------------------------------
__global__ __launch_bounds__(512, 2) void moe_gemm(
    const unsigned short* __restrict__ xb,   // [T][D] bf16
    const unsigned short* __restrict__ wt,   // [E][H][D] bf16
    const float* __restrict__ be,            // [E][H]
    const int* __restrict__ slot_token,
    const int* __restrict__ meta,
    const int* __restrict__ counts,
    unsigned short* __restrict__ y_slot)     // [SLOT_CAP][H] bf16
{
    __shared__ __align__(16) unsigned short As[4][256 * 32];   // 64 KB
    __shared__ __align__(16) unsigned short Bs[4][256 * 32];   // 64 KB

    // XCD-aware bijective remap: f in [0, 288), xcd = f & 7, chunk = 36.
    int f   = blockIdx.y * gridDim.x + blockIdx.x;
    int wid = (f & 7) * 36 + (f >> 3);
    int m0 = (wid >> 2) * 256;
    if (m0 >= meta[NEXP]) return;
    int n0 = (wid & 3) * 256;

    int e = 0;
    #pragma unroll
    for (int i = 1; i < NEXP; i++) if (m0 >= meta[i]) e = i;
    int lim = meta[e] + counts[e];           // slots >= lim are padding

    int tid  = threadIdx.x;
    int lane = tid & 63, wv = tid >> 6;

    // Staging geometry: wave wv stages rows 16wv..16wv+15 (+128 second
    // round) of both A and B; lane covers row 16wv+(lane>>2), col-group
    // lane&3 (LDS linear; source col pre-swizzled by (row>>1)&3).
    int rS  = 16 * wv + (lane >> 2);                 // 0..127
    int kc  = (((lane & 3) ^ ((rS >> 1) & 3)) * 8);  // swizzled source col
    int c0  = wv * 512;                              // LDS shorts offset
    int c1  = 4096 + wv * 512;

    int sA0 = m0 + rS, sA1 = sA0 + 128;
    int tA0 = (sA0 < lim) ? slot_token[sA0] : 0;
    int tA1 = (sA1 < lim) ? slot_token[sA1] : 0;
    const unsigned short* gA0 = xb + (size_t)tA0 * DDIM + kc;
    const unsigned short* gA1 = xb + (size_t)tA1 * DDIM + kc;
    const unsigned short* gB0 = wt + ((size_t)e * HDIM + n0 + rS) * DDIM + kc;
    const unsigned short* gB1 = gB0 + (size_t)128 * DDIM;

    f32x4 acc[8][4];
    #pragma unroll
    for (int i = 0; i < 8; i++)
        #pragma unroll
        for (int j = 0; j < 4; j++) acc[i][j] = (f32x4){0.f, 0.f, 0.f, 0.f};

    // Wave tile: wm in {0,128}, wn in {0,64,128,192}.
    int wm = (wv >> 2) * 128, wn = (wv & 3) * 64;
    int l16 = lane & 15, quad = lane >> 4;
    int ff = (l16 >> 1) & 3;
    int rdA[8], rdB[4];
    #pragma unroll
    for (int i = 0; i < 8; i++)
        rdA[i] = (wm + i * 16 + l16) * 32 + ((quad ^ ff) * 8);
    #pragma unroll
    for (int j = 0; j < 4; j++)
        rdB[j] = (wn + j * 16 + l16) * 32 + ((quad ^ ff) * 8);

#define STAGE_A(kt, Ab)                                                       \
    {                                                                         \
        int ko = (kt) * 32;                                                   \
        GLD16(gA0 + ko, (Ab) + c0);                                           \
        GLD16(gA1 + ko, (Ab) + c1);                                           \
    }
#define STAGE_B(kt, Bb)                                                       \
    {                                                                         \
        int ko = (kt) * 32;                                                   \
        GLD16(gB0 + ko, (Bb) + c0);                                           \
        GLD16(gB1 + ko, (Bb) + c1);                                           \
    }

    // Prologue: stage tiles 0 and 1 (4 loads each), wait tile 0 (younger =
    // tile 1's 4 -> vmcnt(4)), barrier.
    STAGE_A(0, As[0]) STAGE_B(0, Bs[0])
    STAGE_A(1, As[1]) STAGE_B(1, Bs[1])
    __builtin_amdgcn_s_waitcnt(0x0F74);  // vmcnt(4)
    __builtin_amdgcn_s_barrier();
    asm volatile("" ::: "memory");

    #pragma unroll 1
    for (int t = 0; t < 32; ++t) {
        unsigned short* Ab = As[t & 3];
        unsigned short* Bb = Bs[t & 3];
        // ---- phase 0: B frags + A frags 0..3, stage A(t+2) ----
        bf16x8 bfr[4];
        #pragma unroll
        for (int j = 0; j < 4; j++) bfr[j] = *(const bf16x8*)(Bb + rdB[j]);
        bf16x8 afr[4];
        #pragma unroll
        for (int i = 0; i < 4; i++) afr[i] = *(const bf16x8*)(Ab + rdA[i]);
        if (t < 30) STAGE_A(t + 2, As[(t + 2) & 3])
        asm volatile("" ::: "memory");
        __builtin_amdgcn_s_barrier();
        asm volatile("" ::: "memory");
        __builtin_amdgcn_s_setprio(1);
        #pragma unroll
        for (int i = 0; i < 4; i++)
            #pragma unroll
            for (int j = 0; j < 4; j++)
                acc[i][j] = __builtin_amdgcn_mfma_f32_16x16x32_bf16(
                    afr[i], bfr[j], acc[i][j], 0, 0, 0);
        __builtin_amdgcn_s_setprio(0);
        asm volatile("" ::: "memory");
        __builtin_amdgcn_s_barrier();
        asm volatile("" ::: "memory");
        // ---- phase 1: A frags 4..7 (B reused in regs), stage B(t+2) ----
        #pragma unroll
        for (int i = 0; i < 4; i++) afr[i] = *(const bf16x8*)(Ab + rdA[i + 4]);
        if (t < 30) STAGE_B(t + 2, Bs[(t + 2) & 3])
        asm volatile("" ::: "memory");
        __builtin_amdgcn_s_barrier();
        asm volatile("" ::: "memory");
        __builtin_amdgcn_s_setprio(1);
        #pragma unroll
        for (int i = 0; i < 4; i++)
            #pragma unroll
            for (int j = 0; j < 4; j++)
                acc[i + 4][j] = __builtin_amdgcn_mfma_f32_16x16x32_bf16(
                    afr[i], bfr[j], acc[i + 4][j], 0, 0, 0);
        __builtin_amdgcn_s_setprio(0);
        // ---- tile boundary: tile t+1 must be resident for next iter.
        // Younger-than-(t+1) loads = tile (t+2)'s 4 when staged (t<30).
        if (t < 30) __builtin_amdgcn_s_waitcnt(0x0F74);  // vmcnt(4)
        else        __builtin_amdgcn_s_waitcnt(0x0F70);  // vmcnt(0)
        __builtin_amdgcn_s_barrier();
        asm volatile("" ::: "memory");
    }
#undef STAGE_A
#undef STAGE_B

    // Epilogue: C/D layout col(n)=l16, row(m)=quad*4+reg. Pad rows skipped.
    #pragma unroll
    for (int i = 0; i < 8; i++) {
        #pragma unroll
        for (int r = 0; r < 4; r++) {
            int slot = m0 + wm + i * 16 + quad * 4 + r;
            if (slot >= lim) continue;
            unsigned short* yp = y_slot + (size_t)slot * HDIM + n0;
            #pragma unroll
            for (int j = 0; j < 4; j++) {
                int col = wn + j * 16 + l16;
                yp[col] = f2b(acc[i][j][r] + be[e * HDIM + n0 + col]);
            }
        }
    }
}

// ---------------------------------------------------------------------------
// K5: combine — out[t] = g0*y[s0] + g1*y[s1]. 2 tokens per block, 16B/lane
// y_slot loads, fully coalesced; overwrites every out element.
// ---------------------------------------------------------------------------
__global__ __launch_bounds__(256) void moe_combine(
    const unsigned short* __restrict__ y_slot,
    const int* __restrict__ tok_slot, const float* __restrict__ tok_g,
    float* __restrict__ out)
{
    int tid  = threadIdx.x;
    int half = tid >> 7;              // 0/1: which token of this block
    int lane = tid & 127;             // 128 lanes x 8 bf16 = 1024 cols
    int t = blockIdx.x * 2 + half;
    int s0 = tok_slot[2 * t], s1 = tok_slot[2 * t + 1];
    float g0 = tok_g[2 * t],  g1 = tok_g[2 * t + 1];
    u16x8 a = ((const u16x8*)(y_slot + (size_t)s0 * HDIM))[lane];
    u16x8 b = ((const u16x8*)(y_slot + (size_t)s1 * HDIM))[lane];
    float4 o0, o1;
    o0.x = g0 * b2f(a[0]) + g1 * b2f(b[0]);
    o0.y = g0 * b2f(a[1]) + g1 * b2f(b[1]);
    o0.z = g0 * b2f(a[2]) + g1 * b2f(b[2]);
    o0.w = g0 * b2f(a[3]) + g1 * b2f(b[3]);
    o1.x = g0 * b2f(a[4]) + g1 * b2f(b[4]);
    o1.y = g0 * b2f(a[5]) + g1 * b2f(b[5]);
    o1.z = g0 * b2f(a[6]) + g1 * b2f(b[6]);
    o1.w = g0 * b2f(a[7]) + g1 * b2f(b[7]);
    float4* op = (float4*)(out + (size_t)t * HDIM) + lane * 2;
    op[0] = o0;
    op[1] = o1;
}

extern "C" void kernel_launch(void* const* d_in, const int* in_sizes, int n_in,
                              void* d_out, int out_size, void* d_ws, size_t ws_size,
                              hipStream_t stream) {
    const float* x  = (const float*)d_in[0];   // [B,S,D] fp32
    const float* wg = (const float*)d_in[1];   // [D,E]
    const float* we = (const float*)d_in[2];   // [E,D,H]
    const float* be = (const float*)d_in[3];   // [E,H]
    float* out = (float*)d_out;

    char* ws = (char*)d_ws;
    size_t o = 0;
    auto alloc = [&](size_t bytes) -> void* {
        void* p = ws + o;
        o = (o + bytes + 255) & ~(size_t)255;
        return p;
    };
    unsigned short* xb   = (unsigned short*)alloc((size_t)T_TOK * DDIM * 2);
    unsigned short* wtb  = (unsigned short*)alloc((size_t)NEXP * HDIM * DDIM * 2);
    unsigned short* ysl  = (unsigned short*)alloc((size_t)SLOT_CAP * HDIM * 2);
    int*   slot_token    = (int*)  alloc((size_t)SLOT_CAP * 4);
    int*   cnt_part      = (int*)  alloc((size_t)NCBLK * NEXP * 4);
    int*   counts        = (int*)  alloc(NEXP * 4);
    int*   meta          = (int*)  alloc((NEXP + 1) * 4);
    int*   tok_e         = (int*)  alloc((size_t)T_TOK * 2 * 4);
    float* tok_g         = (float*)alloc((size_t)T_TOK * 2 * 4);
    int*   tok_slot      = (int*)  alloc((size_t)T_TOK * 2 * 4);

    // 6 graph nodes, no memsets, no global cursor.
    moe_routing<<<T_TOK / 4, 256, 0, stream>>>(x, wg, xb, tok_e, tok_g);
    moe_count<<<NCBLK, 256, 0, stream>>>(tok_e, cnt_part);
    moe_slotfill<<<NCBLK, 256, 0, stream>>>(tok_e, cnt_part, meta, counts,
                                            slot_token, tok_slot);
    moe_wtrans<<<dim3(HDIM / 64, DDIM / 64, NEXP), 256, 0, stream>>>(we, wtb);
    moe_gemm<<<dim3(HDIM / 256, SLOT_CAP / 256), 512, 0, stream>>>(
        xb, wtb, be, slot_token, meta, counts, ysl);
    moe_combine<<<T_TOK / 2, 256, 0, stream>>>(ysl, tok_slot, tok_g, out);
}

// Round 5
// 222.813 us; speedup vs baseline: 1.0328x; 1.0328x over previous
//
#include <hip/hip_runtime.h>
#include <hip/hip_bf16.h>

// Problem constants (fixed by the reference: B=4,S=2048,D=1024,E=8,H=1024)
#define T_TOK 8192
#define DDIM  1024
#define NEXP  8
#define HDIM  1024
#define SLOT_CAP 18432   // 72 M-tiles * 256; >= 16384 + 8*255 padding worst case
#define NCBLK 32         // blocks for count/slotfill

typedef short bf16x8 __attribute__((ext_vector_type(8)));   // 8 bf16 in 4 VGPRs
typedef float f32x4  __attribute__((ext_vector_type(4)));
typedef unsigned short u16x8 __attribute__((ext_vector_type(8)));

typedef const __attribute__((address_space(1))) unsigned int* gas_ptr;
typedef __attribute__((address_space(3))) unsigned int*       las_ptr;
#define GLD16(gp, lp) __builtin_amdgcn_global_load_lds((gas_ptr)(gp), (las_ptr)(lp), 16, 0, 0)

// fp32 -> bf16 round-to-nearest-even
static __device__ __forceinline__ unsigned short f2b(float f) {
    union { float f; unsigned int u; } v; v.f = f;
    unsigned int u = v.u;
    u += 0x7fffu + ((u >> 16) & 1u);
    return (unsigned short)(u >> 16);
}
static __device__ __forceinline__ float b2f(unsigned short h) {
    union { unsigned int u; float f; } v; v.u = ((unsigned int)h) << 16;
    return v.f;
}

// ---------------------------------------------------------------------------
// K1: routing, one WAVE per token (4 tokens/block, no LDS, no barriers).
// fp64 logits (selection-exact), shfl_xor butterfly, fused x->bf16.
// ---------------------------------------------------------------------------
__global__ __launch_bounds__(256) void moe_routing(
    const float* __restrict__ x, const float* __restrict__ wg,
    unsigned short* __restrict__ xb,
    int* __restrict__ tok_e, float* __restrict__ tok_g)
{
    int wv   = threadIdx.x >> 6;        // wave 0..3 -> token
    int lane = threadIdx.x & 63;
    int t    = blockIdx.x * 4 + wv;

    const float4* xr = (const float4*)(x + (size_t)t * DDIM);
    float4 v[4];
    #pragma unroll
    for (int i = 0; i < 4; i++) v[i] = xr[lane + 64 * i];

    ushort4* xw = (ushort4*)(xb + (size_t)t * DDIM);
    #pragma unroll
    for (int i = 0; i < 4; i++) {
        ushort4 s4;
        s4.x = f2b(v[i].x); s4.y = f2b(v[i].y);
        s4.z = f2b(v[i].z); s4.w = f2b(v[i].w);
        xw[lane + 64 * i] = s4;
    }

    double s[NEXP];
    #pragma unroll
    for (int e = 0; e < NEXP; e++) s[e] = 0.0;
    #pragma unroll
    for (int i = 0; i < 4; i++) {
        const float* wr = wg + ((size_t)lane * 4 + 256 * i) * NEXP;
        #pragma unroll
        for (int j = 0; j < 4; j++) {
            double xj = (double)((&v[i].x)[j]);
            #pragma unroll
            for (int e = 0; e < NEXP; e++)
                s[e] += xj * (double)wr[j * NEXP + e];
        }
    }

    #pragma unroll
    for (int off = 32; off > 0; off >>= 1) {
        #pragma unroll
        for (int e = 0; e < NEXP; e++)
            s[e] += __shfl_xor(s[e], off, 64);
    }

    if (lane == 0) {
        int e0 = 0;
        for (int e = 1; e < NEXP; e++) if (s[e] > s[e0]) e0 = e;
        int e1 = (e0 == 0) ? 1 : 0;
        for (int e = 0; e < NEXP; e++) if (e != e0 && s[e] > s[e1]) e1 = e;
        double g0 = 1.0 / (1.0 + exp(s[e1] - s[e0]));
        tok_e[2*t] = e0; tok_e[2*t+1] = e1;
        tok_g[2*t] = (float)g0; tok_g[2*t+1] = (float)(1.0 - g0);
    }
}

// ---------------------------------------------------------------------------
// K2a: per-block expert histogram -> cnt_part[b][e].
// ---------------------------------------------------------------------------
__global__ __launch_bounds__(256) void moe_count(
    const int* __restrict__ tok_e, int* __restrict__ cnt_part)
{
    __shared__ int h[NEXP];
    if (threadIdx.x < NEXP) h[threadIdx.x] = 0;
    __syncthreads();
    int t = blockIdx.x * 256 + threadIdx.x;
    atomicAdd(&h[tok_e[2*t]], 1);
    atomicAdd(&h[tok_e[2*t+1]], 1);
    __syncthreads();
    if (threadIdx.x < NEXP)
        cnt_part[blockIdx.x * NEXP + threadIdx.x] = h[threadIdx.x];
}

// ---------------------------------------------------------------------------
// K2b: redundant reduce of cnt_part per block -> counts + 256-aligned meta
// (gemm M-tile = 256) + deterministic cross-block bases. Block 0 publishes
// meta/counts. prefix+rank is unique per slot.
// ---------------------------------------------------------------------------
__global__ __launch_bounds__(256) void moe_slotfill(
    const int* __restrict__ tok_e, const int* __restrict__ cnt_part,
    int* __restrict__ meta, int* __restrict__ counts,
    int* __restrict__ slot_token, int* __restrict__ tok_slot)
{
    __shared__ int h[NEXP];
    __shared__ int tots[NEXP], pres[NEXP], base[NEXP];
    int tid = threadIdx.x;
    if (tid < NEXP) h[tid] = 0;
    __syncthreads();
    int t = blockIdx.x * 256 + tid;
    int e0 = tok_e[2*t],     e1 = tok_e[2*t + 1];
    int r0 = atomicAdd(&h[e0], 1);
    int r1 = atomicAdd(&h[e1], 1);
    if (tid < NEXP) {
        int pre = 0, tot = 0;
        for (int b = 0; b < NCBLK; b++) {
            int c = cnt_part[b * NEXP + tid];
            if (b < (int)blockIdx.x) pre += c;
            tot += c;
        }
        tots[tid] = tot; pres[tid] = pre;
    }
    __syncthreads();
    if (tid < NEXP) {
        int off = 0;
        for (int e = 0; e < tid; e++) off += (tots[e] + 255) & ~255;
        base[tid] = off + pres[tid];
        if (blockIdx.x == 0) {
            meta[tid]   = off;
            counts[tid] = tots[tid];
            if (tid == NEXP - 1) meta[NEXP] = off + ((tots[tid] + 255) & ~255);
        }
    }
    __syncthreads();
    int s0 = base[e0] + r0, s1 = base[e1] + r1;
    slot_token[s0] = t;  tok_slot[2*t]     = s0;
    slot_token[s1] = t;  tok_slot[2*t + 1] = s1;
}

// K3: We [E][D][H] fp32 -> Wt [E][H][D] bf16 (transpose for GEMM B loads).
__global__ __launch_bounds__(256) void moe_wtrans(
    const float* __restrict__ we, unsigned short* __restrict__ wt)
{
    __shared__ unsigned short tile[64][65];
    int e  = blockIdx.z;
    int d0 = blockIdx.y * 64;
    int h0 = blockIdx.x * 64;
    int c  = threadIdx.x & 63;
    int r4 = threadIdx.x >> 6;
    #pragma unroll
    for (int i = 0; i < 64; i += 4)
        tile[r4 + i][c] = f2b(we[((size_t)e * DDIM + d0 + r4 + i) * HDIM + h0 + c]);
    __syncthreads();
    #pragma unroll
    for (int i = 0; i < 64; i += 4)
        wt[((size_t)e * HDIM + h0 + r4 + i) * DDIM + d0 + c] = tile[c][r4 + i];
}

// ---------------------------------------------------------------------------
// K4 (R11): 256x128-tile grouped gather-GEMM, R8's proven 1-barrier K-loop
// skeleton at 512 threads / 8 waves (4M x 2N, each wave 64x64 = R8's exact
// per-wave geometry). R10 post-mortem: 256^2 @ 1 blk/CU quantized the
// makespan to 2 full rounds (272 blocks on 256 CUs) — grid granularity ate
// more than the schedule gained. This config:
//   - bytes/FLOP (256+128)/(256*128) = 1/85 vs R8's 1/64 (1.33x intensity)
//   - A,B both ring-3, lead-2, ONE counted wait + ONE barrier per K-tile:
//     3 GLD16/thread/tile (2 A + 1 B); at iter t, younger-than-tile-(t+1)
//     loads = tile (t+2)'s 3 -> steady vmcnt(3), vmcnt(0) at t=31.
//     WAR: stage target (t+2)%3 == (t-1)%3, whose ds_reads all retired
//     before barrier t (operands consumed by MFMA pre-barrier) — R8 proof.
//   - LDS 3x(16+8)KB = 72KB -> 2 blocks/CU, 16 waves/CU: cross-block TLP
//     covers the boundary wait; grid 72x8=576 (%8==0), quantization
//     granularity ~1/4 of R10's.
// XCD remap: chunk 72, 8 consecutive wid share one A-panel.
// ---------------------------------------------------------------------------
__global__ __launch_bounds__(512, 4) void moe_gemm(
    const unsigned short* __restrict__ xb,   // [T][D] bf16
    const unsigned short* __restrict__ wt,   // [E][H][D] bf16
    const float* __restrict__ be,            // [E][H]
    const int* __restrict__ slot_token,
    const int* __restrict__ meta,
    const int* __restrict__ counts,
    unsigned short* __restrict__ y_slot)     // [SLOT_CAP][H] bf16
{
    __shared__ __align__(16) unsigned short As[3][256 * 32];   // 48 KB
    __shared__ __align__(16) unsigned short Bs[3][128 * 32];   // 24 KB

    // XCD-aware bijective remap: f in [0, 576), xcd = f & 7, chunk = 72.
    int f   = blockIdx.y * gridDim.x + blockIdx.x;
    int wid = (f & 7) * 72 + (f >> 3);
    int m0 = (wid >> 3) * 256;
    if (m0 >= meta[NEXP]) return;
    int n0 = (wid & 7) * 128;

    int e = 0;
    #pragma unroll
    for (int i = 1; i < NEXP; i++) if (m0 >= meta[i]) e = i;
    int lim = meta[e] + counts[e];           // slots >= lim are padding

    int tid  = threadIdx.x;
    int lane = tid & 63, wv = tid >> 6;

    // Staging geometry: wave wv covers rows 16wv..16wv+15 (lane>>2) x
    // col-group lane&3. A: two 128-row halves (c0, c1); B: one 128-row set.
    // GLD16 dest = wave-uniform base + lane*16B: 16 rows x 64B contiguous.
    int rS  = 16 * wv + (lane >> 2);                 // 0..127
    int kc  = (((lane & 3) ^ ((rS >> 1) & 3)) * 8);  // swizzled source col
    // (+128-row offset leaves (row>>1)&3 unchanged: 128>>1 = 64, &3 == 0)
    int c0  = wv * 512;                              // LDS shorts offset
    int c1  = 4096 + wv * 512;                       // A rows 128..255

    int sA0 = m0 + rS, sA1 = sA0 + 128;
    int tA0 = (sA0 < lim) ? slot_token[sA0] : 0;
    int tA1 = (sA1 < lim) ? slot_token[sA1] : 0;
    const unsigned short* gA0 = xb + (size_t)tA0 * DDIM + kc;
    const unsigned short* gA1 = xb + (size_t)tA1 * DDIM + kc;
    const unsigned short* gB0 = wt + ((size_t)e * HDIM + n0 + rS) * DDIM + kc;

    f32x4 acc[4][4];
    #pragma unroll
    for (int i = 0; i < 4; i++)
        #pragma unroll
        for (int j = 0; j < 4; j++) acc[i][j] = (f32x4){0.f, 0.f, 0.f, 0.f};

    // Wave tile: wm in {0,64,128,192}, wn in {0,64}.
    int wm = (wv >> 1) * 64, wn = (wv & 1) * 64;
    int l16 = lane & 15, quad = lane >> 4;
    int ff = (l16 >> 1) & 3;
    int rdA[4], rdB[4];
    #pragma unroll
    for (int i = 0; i < 4; i++) {
        rdA[i] = (wm + i * 16 + l16) * 32 + ((quad ^ ff) * 8);
        rdB[i] = (wn + i * 16 + l16) * 32 + ((quad ^ ff) * 8);
    }

#define STAGE(kt, Ab, Bb)                                                     \
    {                                                                         \
        int ko = (kt) * 32;                                                   \
        GLD16(gA0 + ko, (Ab) + c0);                                           \
        GLD16(gA1 + ko, (Ab) + c1);                                           \
        GLD16(gB0 + ko, (Bb) + c0);                                           \
    }
#define COMPUTE(Ab, Bb)                                                       \
    {                                                                         \
        bf16x8 bfr[4];                                                        \
        _Pragma("unroll")                                                     \
        for (int j = 0; j < 4; j++)                                           \
            bfr[j] = *(const bf16x8*)((Bb) + rdB[j]);                         \
        _Pragma("unroll")                                                     \
        for (int i = 0; i < 4; i++) {                                         \
            bf16x8 af = *(const bf16x8*)((Ab) + rdA[i]);                      \
            _Pragma("unroll")                                                 \
            for (int j = 0; j < 4; j++)                                       \
                acc[i][j] = __builtin_amdgcn_mfma_f32_16x16x32_bf16(          \
                    af, bfr[j], acc[i][j], 0, 0, 0);                          \
        }                                                                     \
    }

    // Prologue: stage tiles 0,1. First wait: drain tile 0 (leave tile 1's 3).
    STAGE(0, As[0], Bs[0])
    STAGE(1, As[1], Bs[1])

    #pragma unroll 1
    for (int t = 0; t < 32; ++t) {
        asm volatile("" ::: "memory");
        if (t == 31) __builtin_amdgcn_s_waitcnt(0x0F70);  // vmcnt(0) tail
        else         __builtin_amdgcn_s_waitcnt(0x0F73);  // vmcnt(3)
        __builtin_amdgcn_s_barrier();
        asm volatile("" ::: "memory");
        if (t < 30) STAGE(t + 2, As[(t + 2) % 3], Bs[(t + 2) % 3])
        __builtin_amdgcn_s_setprio(1);
        COMPUTE(As[t % 3], Bs[t % 3])
        __builtin_amdgcn_s_setprio(0);
    }
#undef STAGE
#undef COMPUTE

    // Epilogue: C/D layout col(n)=l16, row(m)=quad*4+reg. Pad rows skipped.
    #pragma unroll
    for (int i = 0; i < 4; i++) {
        #pragma unroll
        for (int r = 0; r < 4; r++) {
            int slot = m0 + wm + i * 16 + quad * 4 + r;
            if (slot >= lim) continue;
            unsigned short* yp = y_slot + (size_t)slot * HDIM + n0;
            #pragma unroll
            for (int j = 0; j < 4; j++) {
                int col = wn + j * 16 + l16;
                yp[col] = f2b(acc[i][j][r] + be[e * HDIM + n0 + col]);
            }
        }
    }
}

// ---------------------------------------------------------------------------
// K5: combine — out[t] = g0*y[s0] + g1*y[s1]. 2 tokens per block, 16B/lane
// y_slot loads, fully coalesced; overwrites every out element.
// ---------------------------------------------------------------------------
__global__ __launch_bounds__(256) void moe_combine(
    const unsigned short* __restrict__ y_slot,
    const int* __restrict__ tok_slot, const float* __restrict__ tok_g,
    float* __restrict__ out)
{
    int tid  = threadIdx.x;
    int half = tid >> 7;              // 0/1: which token of this block
    int lane = tid & 127;             // 128 lanes x 8 bf16 = 1024 cols
    int t = blockIdx.x * 2 + half;
    int s0 = tok_slot[2 * t], s1 = tok_slot[2 * t + 1];
    float g0 = tok_g[2 * t],  g1 = tok_g[2 * t + 1];
    u16x8 a = ((const u16x8*)(y_slot + (size_t)s0 * HDIM))[lane];
    u16x8 b = ((const u16x8*)(y_slot + (size_t)s1 * HDIM))[lane];
    float4 o0, o1;
    o0.x = g0 * b2f(a[0]) + g1 * b2f(b[0]);
    o0.y = g0 * b2f(a[1]) + g1 * b2f(b[1]);
    o0.z = g0 * b2f(a[2]) + g1 * b2f(b[2]);
    o0.w = g0 * b2f(a[3]) + g1 * b2f(b[3]);
    o1.x = g0 * b2f(a[4]) + g1 * b2f(b[4]);
    o1.y = g0 * b2f(a[5]) + g1 * b2f(b[5]);
    o1.z = g0 * b2f(a[6]) + g1 * b2f(b[6]);
    o1.w = g0 * b2f(a[7]) + g1 * b2f(b[7]);
    float4* op = (float4*)(out + (size_t)t * HDIM) + lane * 2;
    op[0] = o0;
    op[1] = o1;
}

extern "C" void kernel_launch(void* const* d_in, const int* in_sizes, int n_in,
                              void* d_out, int out_size, void* d_ws, size_t ws_size,
                              hipStream_t stream) {
    const float* x  = (const float*)d_in[0];   // [B,S,D] fp32
    const float* wg = (const float*)d_in[1];   // [D,E]
    const float* we = (const float*)d_in[2];   // [E,D,H]
    const float* be = (const float*)d_in[3];   // [E,H]
    float* out = (float*)d_out;

    char* ws = (char*)d_ws;
    size_t o = 0;
    auto alloc = [&](size_t bytes) -> void* {
        void* p = ws + o;
        o = (o + bytes + 255) & ~(size_t)255;
        return p;
    };
    unsigned short* xb   = (unsigned short*)alloc((size_t)T_TOK * DDIM * 2);
    unsigned short* wtb  = (unsigned short*)alloc((size_t)NEXP * HDIM * DDIM * 2);
    unsigned short* ysl  = (unsigned short*)alloc((size_t)SLOT_CAP * HDIM * 2);
    int*   slot_token    = (int*)  alloc((size_t)SLOT_CAP * 4);
    int*   cnt_part      = (int*)  alloc((size_t)NCBLK * NEXP * 4);
    int*   counts        = (int*)  alloc(NEXP * 4);
    int*   meta          = (int*)  alloc((NEXP + 1) * 4);
    int*   tok_e         = (int*)  alloc((size_t)T_TOK * 2 * 4);
    float* tok_g         = (float*)alloc((size_t)T_TOK * 2 * 4);
    int*   tok_slot      = (int*)  alloc((size_t)T_TOK * 2 * 4);

    // 6 graph nodes, no memsets, no global cursor.
    moe_routing<<<T_TOK / 4, 256, 0, stream>>>(x, wg, xb, tok_e, tok_g);
    moe_count<<<NCBLK, 256, 0, stream>>>(tok_e, cnt_part);
    moe_slotfill<<<NCBLK, 256, 0, stream>>>(tok_e, cnt_part, meta, counts,
                                            slot_token, tok_slot);
    moe_wtrans<<<dim3(HDIM / 64, DDIM / 64, NEXP), 256, 0, stream>>>(we, wtb);
    moe_gemm<<<dim3(HDIM / 128, SLOT_CAP / 256), 512, 0, stream>>>(
        xb, wtb, be, slot_token, meta, counts, ysl);
    moe_combine<<<T_TOK / 2, 256, 0, stream>>>(ysl, tok_slot, tok_g, out);
}

// Round 7
// 209.383 us; speedup vs baseline: 1.0990x; 1.0641x over previous
//
#include <hip/hip_runtime.h>
#include <hip/hip_bf16.h>

// Problem constants (fixed by the reference: B=4,S=2048,D=1024,E=8,H=1024)
#define T_TOK 8192
#define DDIM  1024
#define NEXP  8
#define HDIM  1024
#define SLOT_CAP 17536   // 137 M-tiles * 128; >= 16384 + 8*127 padding worst case
#define NCBLK 32         // blocks for count/slotfill

typedef short bf16x8 __attribute__((ext_vector_type(8)));   // 8 bf16 in 4 VGPRs
typedef float f32x4  __attribute__((ext_vector_type(4)));
typedef unsigned short u16x8 __attribute__((ext_vector_type(8)));

typedef const __attribute__((address_space(1))) unsigned int* gas_ptr;
typedef __attribute__((address_space(3))) unsigned int*       las_ptr;
#define GLD16(gp, lp) __builtin_amdgcn_global_load_lds((gas_ptr)(gp), (las_ptr)(lp), 16, 0, 0)

// fp32 -> bf16 round-to-nearest-even
static __device__ __forceinline__ unsigned short f2b(float f) {
    union { float f; unsigned int u; } v; v.f = f;
    unsigned int u = v.u;
    u += 0x7fffu + ((u >> 16) & 1u);
    return (unsigned short)(u >> 16);
}
static __device__ __forceinline__ float b2f(unsigned short h) {
    union { unsigned int u; float f; } v; v.u = ((unsigned int)h) << 16;
    return v.f;
}

// ---------------------------------------------------------------------------
// K1 (R12): routing FUSED with wtrans via blockIdx split (saves one node +
// lets the two memory-bound kernels share the machine). Blocks 0..2047:
// wave-per-token routing (R9 design, fp64 logits, shfl_xor butterfly, fused
// x->bf16). Blocks 2048..4095: We [E][D][H] fp32 -> Wt [E][H][D] bf16.
// ---------------------------------------------------------------------------
__global__ __launch_bounds__(256) void moe_route_wtrans(
    const float* __restrict__ x, const float* __restrict__ wg,
    const float* __restrict__ we,
    unsigned short* __restrict__ xb, unsigned short* __restrict__ wt,
    int* __restrict__ tok_e, float* __restrict__ tok_g)
{
    __shared__ unsigned short tile[64][65];
    int bid = blockIdx.x;
    if (bid < 2048) {
        // ---- routing: 4 tokens per block, one wave each ----
        int wv   = threadIdx.x >> 6;
        int lane = threadIdx.x & 63;
        int t    = bid * 4 + wv;

        const float4* xr = (const float4*)(x + (size_t)t * DDIM);
        float4 v[4];
        #pragma unroll
        for (int i = 0; i < 4; i++) v[i] = xr[lane + 64 * i];

        ushort4* xw = (ushort4*)(xb + (size_t)t * DDIM);
        #pragma unroll
        for (int i = 0; i < 4; i++) {
            ushort4 s4;
            s4.x = f2b(v[i].x); s4.y = f2b(v[i].y);
            s4.z = f2b(v[i].z); s4.w = f2b(v[i].w);
            xw[lane + 64 * i] = s4;
        }

        double s[NEXP];
        #pragma unroll
        for (int e = 0; e < NEXP; e++) s[e] = 0.0;
        #pragma unroll
        for (int i = 0; i < 4; i++) {
            const float* wr = wg + ((size_t)lane * 4 + 256 * i) * NEXP;
            #pragma unroll
            for (int j = 0; j < 4; j++) {
                double xj = (double)((&v[i].x)[j]);
                #pragma unroll
                for (int e = 0; e < NEXP; e++)
                    s[e] += xj * (double)wr[j * NEXP + e];
            }
        }
        #pragma unroll
        for (int off = 32; off > 0; off >>= 1) {
            #pragma unroll
            for (int e = 0; e < NEXP; e++)
                s[e] += __shfl_xor(s[e], off, 64);
        }
        if (lane == 0) {
            int e0 = 0;
            for (int e = 1; e < NEXP; e++) if (s[e] > s[e0]) e0 = e;
            int e1 = (e0 == 0) ? 1 : 0;
            for (int e = 0; e < NEXP; e++) if (e != e0 && s[e] > s[e1]) e1 = e;
            double g0 = 1.0 / (1.0 + exp(s[e1] - s[e0]));
            tok_e[2*t] = e0; tok_e[2*t+1] = e1;
            tok_g[2*t] = (float)g0; tok_g[2*t+1] = (float)(1.0 - g0);
        }
    } else {
        // ---- wtrans: 64x64 tile transpose, id -> (e, d0, h0) ----
        int id = bid - 2048;
        int e  = id >> 8;
        int d0 = ((id >> 4) & 15) * 64;
        int h0 = (id & 15) * 64;
        int c  = threadIdx.x & 63;
        int r4 = threadIdx.x >> 6;
        #pragma unroll
        for (int i = 0; i < 64; i += 4)
            tile[r4 + i][c] = f2b(we[((size_t)e * DDIM + d0 + r4 + i) * HDIM + h0 + c]);
        __syncthreads();
        #pragma unroll
        for (int i = 0; i < 64; i += 4)
            wt[((size_t)e * HDIM + h0 + r4 + i) * DDIM + d0 + c] = tile[c][r4 + i];
    }
}

// ---------------------------------------------------------------------------
// K2a: per-block expert histogram -> cnt_part[b][e].
// ---------------------------------------------------------------------------
__global__ __launch_bounds__(256) void moe_count(
    const int* __restrict__ tok_e, int* __restrict__ cnt_part)
{
    __shared__ int h[NEXP];
    if (threadIdx.x < NEXP) h[threadIdx.x] = 0;
    __syncthreads();
    int t = blockIdx.x * 256 + threadIdx.x;
    atomicAdd(&h[tok_e[2*t]], 1);
    atomicAdd(&h[tok_e[2*t+1]], 1);
    __syncthreads();
    if (threadIdx.x < NEXP)
        cnt_part[blockIdx.x * NEXP + threadIdx.x] = h[threadIdx.x];
}

// ---------------------------------------------------------------------------
// K2b: redundant reduce of cnt_part per block -> counts + 128-aligned meta
// (gemm M-tile back to 128) + deterministic cross-block bases. Block 0
// publishes meta/counts. prefix+rank is unique per slot.
// ---------------------------------------------------------------------------
__global__ __launch_bounds__(256) void moe_slotfill(
    const int* __restrict__ tok_e, const int* __restrict__ cnt_part,
    int* __restrict__ meta, int* __restrict__ counts,
    int* __restrict__ slot_token, int* __restrict__ tok_slot)
{
    __shared__ int h[NEXP];
    __shared__ int tots[NEXP], pres[NEXP], base[NEXP];
    int tid = threadIdx.x;
    if (tid < NEXP) h[tid] = 0;
    __syncthreads();
    int t = blockIdx.x * 256 + tid;
    int e0 = tok_e[2*t],     e1 = tok_e[2*t + 1];
    int r0 = atomicAdd(&h[e0], 1);
    int r1 = atomicAdd(&h[e1], 1);
    if (tid < NEXP) {
        int pre = 0, tot = 0;
        for (int b = 0; b < NCBLK; b++) {
            int c = cnt_part[b * NEXP + tid];
            if (b < (int)blockIdx.x) pre += c;
            tot += c;
        }
        tots[tid] = tot; pres[tid] = pre;
    }
    __syncthreads();
    if (tid < NEXP) {
        int off = 0;
        for (int e = 0; e < tid; e++) off += (tots[e] + 127) & ~127;
        base[tid] = off + pres[tid];
        if (blockIdx.x == 0) {
            meta[tid]   = off;
            counts[tid] = tots[tid];
            if (tid == NEXP - 1) meta[NEXP] = off + ((tots[tid] + 127) & ~127);
        }
    }
    __syncthreads();
    int s0 = base[e0] + r0, s1 = base[e1] + r1;
    slot_token[s0] = t;  tok_slot[2*t]     = s0;
    slot_token[s1] = t;  tok_slot[2*t + 1] = s1;
}

// ---------------------------------------------------------------------------
// K4 (R12: REVERT to the R2-measured-best kernel, 63.6-64.5 us). 128x128
// tile, 256 thr, XCD remap, A+B ring-3 lead-2, uniform vmcnt(4) steady wait,
// LDS 48KB -> 3 blk/CU. R10/R11 lesson (both regressed): makespan =
// ceil(blocks/resident-slots) x T_block, T_block ~invariant to sharing; the
// 512-thr big-tile engines always land just above a capacity multiple
// (272/256, 544/512) and pay a full extra layer. This config's finer
// granularity (1096 blocks, 768 slots) is the best measured compromise.
// ---------------------------------------------------------------------------
__global__ __launch_bounds__(256, 3) void moe_gemm(
    const unsigned short* __restrict__ xb,   // [T][D] bf16
    const unsigned short* __restrict__ wt,   // [E][H][D] bf16
    const float* __restrict__ be,            // [E][H]
    const int* __restrict__ slot_token,
    const int* __restrict__ meta,
    const int* __restrict__ counts,
    unsigned short* __restrict__ y_slot)     // [SLOT_CAP][H] bf16
{
    __shared__ __align__(16) unsigned short As[3][128 * 32];   // 24 KB
    __shared__ __align__(16) unsigned short Bs[3][128 * 32];   // 24 KB

    // XCD-aware bijective remap (T1): f in [0, 8*137), xcd = f & 7.
    int f   = blockIdx.y * gridDim.x + blockIdx.x;
    int wid = (f & 7) * gridDim.y + (f >> 3);     // chunk = nblk/8 = gridDim.y
    int m0 = (wid >> 3) * 128;
    if (m0 >= meta[NEXP]) return;
    int n0 = (wid & 7) * 128;

    int e = 0;
    #pragma unroll
    for (int i = 1; i < NEXP; i++) if (m0 >= meta[i]) e = i;
    int lim = meta[e] + counts[e];           // slots >= lim are padding

    int tid  = threadIdx.x;
    int lane = tid & 63, wv = tid >> 6;

    // Staging geometry: wave w owns 16-row chunks 2w,2w+1 of A and B.
    int rA = 32 * wv + (lane >> 2);
    int kc = (((lane & 3) ^ ((rA >> 1) & 3)) * 8);   // swizzled source column
    int sA0 = m0 + rA, sA1 = sA0 + 16;
    int tA0 = (sA0 < lim) ? slot_token[sA0] : 0;
    int tA1 = (sA1 < lim) ? slot_token[sA1] : 0;
    const unsigned short* gA0 = xb + (size_t)tA0 * DDIM + kc;
    const unsigned short* gA1 = xb + (size_t)tA1 * DDIM + kc;
    const unsigned short* gB0 = wt + ((size_t)e * HDIM + n0 + rA) * DDIM + kc;
    const unsigned short* gB1 = gB0 + (size_t)16 * DDIM;
    int c0 = (2 * wv) * 512;
    int c1 = c0 + 512;

    f32x4 acc[4][4];
    #pragma unroll
    for (int i = 0; i < 4; i++)
        #pragma unroll
        for (int j = 0; j < 4; j++) acc[i][j] = (f32x4){0.f, 0.f, 0.f, 0.f};

    int wm = (wv >> 1) * 64, wn = (wv & 1) * 64;
    int l16 = lane & 15, quad = lane >> 4;
    int ff = (l16 >> 1) & 3;
    int rdA[4], rdB[4];
    #pragma unroll
    for (int i = 0; i < 4; i++) {
        rdA[i] = (wm + i * 16 + l16) * 32 + ((quad ^ ff) * 8);
        rdB[i] = (wn + i * 16 + l16) * 32 + ((quad ^ ff) * 8);
    }

#define ISSUE_A(kkv, Ab)                                                      \
    {                                                                         \
        int ko = (kkv) * 32;                                                  \
        GLD16(gA0 + ko, (Ab) + c0);                                           \
        GLD16(gA1 + ko, (Ab) + c1);                                           \
    }
#define ISSUE_B(kkv, Bb)                                                      \
    {                                                                         \
        int ko = (kkv) * 32;                                                  \
        GLD16(gB0 + ko, (Bb) + c0);                                           \
        GLD16(gB1 + ko, (Bb) + c1);                                           \
    }
#define COMPUTE(Ab, Bb)                                                       \
    {                                                                         \
        bf16x8 bfr[4];                                                        \
        _Pragma("unroll")                                                     \
        for (int j = 0; j < 4; j++)                                           \
            bfr[j] = *(const bf16x8*)((Bb) + rdB[j]);                         \
        _Pragma("unroll")                                                     \
        for (int i = 0; i < 4; i++) {                                         \
            bf16x8 af = *(const bf16x8*)((Ab) + rdA[i]);                      \
            _Pragma("unroll")                                                 \
            for (int j = 0; j < 4; j++)                                       \
                acc[i][j] = __builtin_amdgcn_mfma_f32_16x16x32_bf16(          \
                    af, bfr[j], acc[i][j], 0, 0, 0);                          \
        }                                                                     \
    }

    unsigned short *A0 = As[0], *A1 = As[1], *A2 = As[2];
    unsigned short *B0 = Bs[0], *B1 = Bs[1], *B2 = Bs[2];

    // Prologue FIFO: A(0),B(0),A(1),B(1). Steady wait vmcnt(4) retires
    // everything through step (k-2)'s issues = {A(k),B(k)} exactly.
    ISSUE_A(0, A0)
    ISSUE_B(0, B0)
    ISSUE_A(1, A1)
    ISSUE_B(1, B1)

    #pragma unroll 1
    for (int kk = 0; kk < 32; ++kk) {
        asm volatile("" ::: "memory");
        if (kk == 31) __builtin_amdgcn_s_waitcnt(0x0F70);  // vmcnt(0) tail
        else          __builtin_amdgcn_s_waitcnt(0x0F74);  // vmcnt(4)
        __builtin_amdgcn_s_barrier();
        asm volatile("" ::: "memory");
        if (kk < 30) {                        // issue BEFORE compute: loads
            ISSUE_B(kk + 2, B2)               // fly under the MFMA phase too
            ISSUE_A(kk + 2, A2)
        }
        COMPUTE(A0, B0)
        unsigned short* tA = A0; A0 = A1; A1 = A2; A2 = tA;
        unsigned short* tB = B0; B0 = B1; B1 = tB; tB = B1; // rotate B 3-way
        B1 = B2; B2 = tB;
    }
#undef ISSUE_A
#undef ISSUE_B
#undef COMPUTE

    // Epilogue: C/D layout col(n)=l16, row(m)=quad*4+reg. Pad rows skipped.
    #pragma unroll
    for (int i = 0; i < 4; i++) {
        #pragma unroll
        for (int r = 0; r < 4; r++) {
            int slot = m0 + wm + i * 16 + quad * 4 + r;
            if (slot >= lim) continue;
            unsigned short* yp = y_slot + (size_t)slot * HDIM + n0;
            #pragma unroll
            for (int j = 0; j < 4; j++) {
                int col = wn + j * 16 + l16;
                yp[col] = f2b(acc[i][j][r] + be[e * HDIM + n0 + col]);
            }
        }
    }
}

// ---------------------------------------------------------------------------
// K5: combine — out[t] = g0*y[s0] + g1*y[s1]. 2 tokens per block, 16B/lane
// y_slot loads, fully coalesced; overwrites every out element.
// ---------------------------------------------------------------------------
__global__ __launch_bounds__(256) void moe_combine(
    const unsigned short* __restrict__ y_slot,
    const int* __restrict__ tok_slot, const float* __restrict__ tok_g,
    float* __restrict__ out)
{
    int tid  = threadIdx.x;
    int half = tid >> 7;              // 0/1: which token of this block
    int lane = tid & 127;             // 128 lanes x 8 bf16 = 1024 cols
    int t = blockIdx.x * 2 + half;
    int s0 = tok_slot[2 * t], s1 = tok_slot[2 * t + 1];
    float g0 = tok_g[2 * t],  g1 = tok_g[2 * t + 1];
    u16x8 a = ((const u16x8*)(y_slot + (size_t)s0 * HDIM))[lane];
    u16x8 b = ((const u16x8*)(y_slot + (size_t)s1 * HDIM))[lane];
    float4 o0, o1;
    o0.x = g0 * b2f(a[0]) + g1 * b2f(b[0]);
    o0.y = g0 * b2f(a[1]) + g1 * b2f(b[1]);
    o0.z = g0 * b2f(a[2]) + g1 * b2f(b[2]);
    o0.w = g0 * b2f(a[3]) + g1 * b2f(b[3]);
    o1.x = g0 * b2f(a[4]) + g1 * b2f(b[4]);
    o1.y = g0 * b2f(a[5]) + g1 * b2f(b[5]);
    o1.z = g0 * b2f(a[6]) + g1 * b2f(b[6]);
    o1.w = g0 * b2f(a[7]) + g1 * b2f(b[7]);
    float4* op = (float4*)(out + (size_t)t * HDIM) + lane * 2;
    op[0] = o0;
    op[1] = o1;
}

extern "C" void kernel_launch(void* const* d_in, const int* in_sizes, int n_in,
                              void* d_out, int out_size, void* d_ws, size_t ws_size,
                              hipStream_t stream) {
    const float* x  = (const float*)d_in[0];   // [B,S,D] fp32
    const float* wg = (const float*)d_in[1];   // [D,E]
    const float* we = (const float*)d_in[2];   // [E,D,H]
    const float* be = (const float*)d_in[3];   // [E,H]
    float* out = (float*)d_out;

    char* ws = (char*)d_ws;
    size_t o = 0;
    auto alloc = [&](size_t bytes) -> void* {
        void* p = ws + o;
        o = (o + bytes + 255) & ~(size_t)255;
        return p;
    };
    unsigned short* xb   = (unsigned short*)alloc((size_t)T_TOK * DDIM * 2);
    unsigned short* wtb  = (unsigned short*)alloc((size_t)NEXP * HDIM * DDIM * 2);
    unsigned short* ysl  = (unsigned short*)alloc((size_t)SLOT_CAP * HDIM * 2);
    int*   slot_token    = (int*)  alloc((size_t)SLOT_CAP * 4);
    int*   cnt_part      = (int*)  alloc((size_t)NCBLK * NEXP * 4);
    int*   counts        = (int*)  alloc(NEXP * 4);
    int*   meta          = (int*)  alloc((NEXP + 1) * 4);
    int*   tok_e         = (int*)  alloc((size_t)T_TOK * 2 * 4);
    float* tok_g         = (float*)alloc((size_t)T_TOK * 2 * 4);
    int*   tok_slot      = (int*)  alloc((size_t)T_TOK * 2 * 4);

    // 5 graph nodes (routing+wtrans fused), no memsets, no global cursor.
    moe_route_wtrans<<<4096, 256, 0, stream>>>(x, wg, we, xb, wtb, tok_e, tok_g);
    moe_count<<<NCBLK, 256, 0, stream>>>(tok_e, cnt_part);
    moe_slotfill<<<NCBLK, 256, 0, stream>>>(tok_e, cnt_part, meta, counts,
                                            slot_token, tok_slot);
    moe_gemm<<<dim3(HDIM / 128, SLOT_CAP / 128), 256, 0, stream>>>(
        xb, wtb, be, slot_token, meta, counts, ysl);
    moe_combine<<<T_TOK / 2, 256, 0, stream>>>(ysl, tok_slot, tok_g, out);
}

// Round 8
// 199.797 us; speedup vs baseline: 1.1518x; 1.0480x over previous
//
#include <hip/hip_runtime.h>
#include <hip/hip_bf16.h>

// Problem constants (fixed by the reference: B=4,S=2048,D=1024,E=8,H=1024)
#define T_TOK 8192
#define DDIM  1024
#define NEXP  8
#define HDIM  1024
#define SLOT_CAP 18048   // 94 M-tiles * 192 >= 16384 + 8*191 worst case
#define NCBLK 32         // blocks for count/slotfill

typedef short bf16x8 __attribute__((ext_vector_type(8)));   // 8 bf16 in 4 VGPRs
typedef float f32x4  __attribute__((ext_vector_type(4)));
typedef unsigned short u16x8 __attribute__((ext_vector_type(8)));

typedef const __attribute__((address_space(1))) unsigned int* gas_ptr;
typedef __attribute__((address_space(3))) unsigned int*       las_ptr;
#define GLD16(gp, lp) __builtin_amdgcn_global_load_lds((gas_ptr)(gp), (las_ptr)(lp), 16, 0, 0)

// fp32 -> bf16 round-to-nearest-even
static __device__ __forceinline__ unsigned short f2b(float f) {
    union { float f; unsigned int u; } v; v.f = f;
    unsigned int u = v.u;
    u += 0x7fffu + ((u >> 16) & 1u);
    return (unsigned short)(u >> 16);
}
static __device__ __forceinline__ float b2f(unsigned short h) {
    union { unsigned int u; float f; } v; v.u = ((unsigned int)h) << 16;
    return v.f;
}

// ---------------------------------------------------------------------------
// K1: routing FUSED with wtrans via blockIdx split. Blocks 0..2047: wave-per-
// token routing (fp64 logits, shfl_xor butterfly, fused x->bf16). Blocks
// 2048..4095: We [E][D][H] fp32 -> Wt [E][H][D] bf16. (R12, measured-good.)
// ---------------------------------------------------------------------------
__global__ __launch_bounds__(256) void moe_route_wtrans(
    const float* __restrict__ x, const float* __restrict__ wg,
    const float* __restrict__ we,
    unsigned short* __restrict__ xb, unsigned short* __restrict__ wt,
    int* __restrict__ tok_e, float* __restrict__ tok_g)
{
    __shared__ unsigned short tile[64][65];
    int bid = blockIdx.x;
    if (bid < 2048) {
        int wv   = threadIdx.x >> 6;
        int lane = threadIdx.x & 63;
        int t    = bid * 4 + wv;

        const float4* xr = (const float4*)(x + (size_t)t * DDIM);
        float4 v[4];
        #pragma unroll
        for (int i = 0; i < 4; i++) v[i] = xr[lane + 64 * i];

        ushort4* xw = (ushort4*)(xb + (size_t)t * DDIM);
        #pragma unroll
        for (int i = 0; i < 4; i++) {
            ushort4 s4;
            s4.x = f2b(v[i].x); s4.y = f2b(v[i].y);
            s4.z = f2b(v[i].z); s4.w = f2b(v[i].w);
            xw[lane + 64 * i] = s4;
        }

        double s[NEXP];
        #pragma unroll
        for (int e = 0; e < NEXP; e++) s[e] = 0.0;
        #pragma unroll
        for (int i = 0; i < 4; i++) {
            const float* wr = wg + ((size_t)lane * 4 + 256 * i) * NEXP;
            #pragma unroll
            for (int j = 0; j < 4; j++) {
                double xj = (double)((&v[i].x)[j]);
                #pragma unroll
                for (int e = 0; e < NEXP; e++)
                    s[e] += xj * (double)wr[j * NEXP + e];
            }
        }
        #pragma unroll
        for (int off = 32; off > 0; off >>= 1) {
            #pragma unroll
            for (int e = 0; e < NEXP; e++)
                s[e] += __shfl_xor(s[e], off, 64);
        }
        if (lane == 0) {
            int e0 = 0;
            for (int e = 1; e < NEXP; e++) if (s[e] > s[e0]) e0 = e;
            int e1 = (e0 == 0) ? 1 : 0;
            for (int e = 0; e < NEXP; e++) if (e != e0 && s[e] > s[e1]) e1 = e;
            double g0 = 1.0 / (1.0 + exp(s[e1] - s[e0]));
            tok_e[2*t] = e0; tok_e[2*t+1] = e1;
            tok_g[2*t] = (float)g0; tok_g[2*t+1] = (float)(1.0 - g0);
        }
    } else {
        int id = bid - 2048;
        int e  = id >> 8;
        int d0 = ((id >> 4) & 15) * 64;
        int h0 = (id & 15) * 64;
        int c  = threadIdx.x & 63;
        int r4 = threadIdx.x >> 6;
        #pragma unroll
        for (int i = 0; i < 64; i += 4)
            tile[r4 + i][c] = f2b(we[((size_t)e * DDIM + d0 + r4 + i) * HDIM + h0 + c]);
        __syncthreads();
        #pragma unroll
        for (int i = 0; i < 64; i += 4)
            wt[((size_t)e * HDIM + h0 + r4 + i) * DDIM + d0 + c] = tile[c][r4 + i];
    }
}

// ---------------------------------------------------------------------------
// K2a: per-block expert histogram -> cnt_part[b][e].
// ---------------------------------------------------------------------------
__global__ __launch_bounds__(256) void moe_count(
    const int* __restrict__ tok_e, int* __restrict__ cnt_part)
{
    __shared__ int h[NEXP];
    if (threadIdx.x < NEXP) h[threadIdx.x] = 0;
    __syncthreads();
    int t = blockIdx.x * 256 + threadIdx.x;
    atomicAdd(&h[tok_e[2*t]], 1);
    atomicAdd(&h[tok_e[2*t+1]], 1);
    __syncthreads();
    if (threadIdx.x < NEXP)
        cnt_part[blockIdx.x * NEXP + threadIdx.x] = h[threadIdx.x];
}

// ---------------------------------------------------------------------------
// K2b: redundant reduce of cnt_part per block -> counts + 192-ALIGNED meta
// (R13: gemm M-tile = 192) + deterministic cross-block bases. Block 0
// publishes meta/counts. prefix+rank is unique per slot.
// ---------------------------------------------------------------------------
__global__ __launch_bounds__(256) void moe_slotfill(
    const int* __restrict__ tok_e, const int* __restrict__ cnt_part,
    int* __restrict__ meta, int* __restrict__ counts,
    int* __restrict__ slot_token, int* __restrict__ tok_slot)
{
    __shared__ int h[NEXP];
    __shared__ int tots[NEXP], pres[NEXP], base[NEXP];
    int tid = threadIdx.x;
    if (tid < NEXP) h[tid] = 0;
    __syncthreads();
    int t = blockIdx.x * 256 + tid;
    int e0 = tok_e[2*t],     e1 = tok_e[2*t + 1];
    int r0 = atomicAdd(&h[e0], 1);
    int r1 = atomicAdd(&h[e1], 1);
    if (tid < NEXP) {
        int pre = 0, tot = 0;
        for (int b = 0; b < NCBLK; b++) {
            int c = cnt_part[b * NEXP + tid];
            if (b < (int)blockIdx.x) pre += c;
            tot += c;
        }
        tots[tid] = tot; pres[tid] = pre;
    }
    __syncthreads();
    if (tid < NEXP) {
        int off = 0;
        for (int e = 0; e < tid; e++) off += ((tots[e] + 191) / 192) * 192;
        base[tid] = off + pres[tid];
        if (blockIdx.x == 0) {
            meta[tid]   = off;
            counts[tid] = tots[tid];
            if (tid == NEXP - 1) meta[NEXP] = off + ((tots[tid] + 191) / 192) * 192;
        }
    }
    __syncthreads();
    int s0 = base[e0] + r0, s1 = base[e1] + r1;
    slot_token[s0] = t;  tok_slot[2*t]     = s0;
    slot_token[s1] = t;  tok_slot[2*t + 1] = s1;
}

// ---------------------------------------------------------------------------
// K4 (R13): 192x128-tile grouped gather-GEMM — quantization fix.
// R12 measured: 1056 blocks on 768 slots (3/CU) -> 2 greedy layers (2nd 37%
// full) = 68.75% efficiency; per-layer rate already at the 2-phase ceiling.
// BM=192: Sum_e ceil(cnt_e/192) <= 8 + 16384/192 <= 94 for ANY routing ->
// <= 752 real blocks <= 768 slots -> ALWAYS one layer.
// LDS: A ring-3 (36KB) + B ring-2 (16KB) = 52KB; 3x52 = 156 <= 160KB -> 3/CU.
// Pipeline (no R1-style FIFO coupling): per iter k issue B(k+1) then A(k+2);
// invariant outstanding at top = [A(k):3, B(k):2, A(k+1):3] = 8 -> wait
// vmcnt(3) retires exactly A(k),B(k); A keeps distance-2 (gather, ~2 iters
// ~7200cy), B distance-1 (~3600cy >> 900cy HBM latency). WAR both rings:
// write target was last read pre-previous-barrier (R8 proof).
// Waves: 2x2, per-wave 96x64, acc[6][4], 24 MFMA : 10 ds_read per k-tile.
// Swizzle unchanged: row+64i preserves (r>>1)&3.
// ---------------------------------------------------------------------------
__global__ __launch_bounds__(256, 3) void moe_gemm(
    const unsigned short* __restrict__ xb,   // [T][D] bf16
    const unsigned short* __restrict__ wt,   // [E][H][D] bf16
    const float* __restrict__ be,            // [E][H]
    const int* __restrict__ slot_token,
    const int* __restrict__ meta,
    const int* __restrict__ counts,
    unsigned short* __restrict__ y_slot)     // [SLOT_CAP][H] bf16
{
    __shared__ __align__(16) unsigned short As[3][192 * 32];   // 36 KB
    __shared__ __align__(16) unsigned short Bs[2][128 * 32];   // 16 KB

    // XCD-aware bijective remap: f in [0, 752), xcd = f & 7, chunk = 94.
    int f   = blockIdx.y * gridDim.x + blockIdx.x;
    int wid = (f & 7) * gridDim.y + (f >> 3);     // gridDim.y = 94
    int m0 = (wid >> 3) * 192;
    if (m0 >= meta[NEXP]) return;
    int n0 = (wid & 7) * 128;

    int e = 0;
    #pragma unroll
    for (int i = 1; i < NEXP; i++) if (m0 >= meta[i]) e = i;
    int lim = meta[e] + counts[e];           // slots >= lim are padding

    int tid  = threadIdx.x;
    int lane = tid & 63, wv = tid >> 6;

    // Staging: load i covers 16 rows starting at 16*(wv+4i).
    // A: i = 0,1,2 (rows 0..191); B: i = 0,1 (rows 0..127).
    // (row + 64i) >> 1 & 3 is i-invariant -> one swizzled col for all loads.
    int rr  = lane >> 2;                              // 0..15 within 16 rows
    int kc  = (((lane & 3) ^ (((16 * wv + rr) >> 1) & 3)) * 8);
    int cL[3];
    #pragma unroll
    for (int i = 0; i < 3; i++) cL[i] = (wv + 4 * i) * 512;  // LDS short offs

    int sA[3]; const unsigned short* gA[3];
    #pragma unroll
    for (int i = 0; i < 3; i++) {
        sA[i] = m0 + 16 * (wv + 4 * i) + rr;
        int tok = (sA[i] < lim) ? slot_token[sA[i]] : 0;
        gA[i] = xb + (size_t)tok * DDIM + kc;
    }
    const unsigned short* gB0 = wt + ((size_t)e * HDIM + n0 + 16 * wv + rr) * DDIM + kc;
    const unsigned short* gB1 = gB0 + (size_t)64 * DDIM;

    f32x4 acc[6][4];
    #pragma unroll
    for (int i = 0; i < 6; i++)
        #pragma unroll
        for (int j = 0; j < 4; j++) acc[i][j] = (f32x4){0.f, 0.f, 0.f, 0.f};

    // Wave tile: wm in {0,96}, wn in {0,64}.
    int wm = (wv >> 1) * 96, wn = (wv & 1) * 64;
    int l16 = lane & 15, quad = lane >> 4;
    int ff = (l16 >> 1) & 3;
    int rdA[6], rdB[4];
    #pragma unroll
    for (int i = 0; i < 6; i++)
        rdA[i] = (wm + i * 16 + l16) * 32 + ((quad ^ ff) * 8);
    #pragma unroll
    for (int j = 0; j < 4; j++)
        rdB[j] = (wn + j * 16 + l16) * 32 + ((quad ^ ff) * 8);

#define ISSUE_A(kt, Ab)                                                       \
    {                                                                         \
        int ko = (kt) * 32;                                                   \
        GLD16(gA[0] + ko, (Ab) + cL[0]);                                      \
        GLD16(gA[1] + ko, (Ab) + cL[1]);                                      \
        GLD16(gA[2] + ko, (Ab) + cL[2]);                                      \
    }
#define ISSUE_B(kt, Bb)                                                       \
    {                                                                         \
        int ko = (kt) * 32;                                                   \
        GLD16(gB0 + ko, (Bb) + cL[0]);                                        \
        GLD16(gB1 + ko, (Bb) + cL[1]);                                        \
    }
#define COMPUTE(Ab, Bb)                                                       \
    {                                                                         \
        bf16x8 bfr[4];                                                        \
        _Pragma("unroll")                                                     \
        for (int j = 0; j < 4; j++)                                           \
            bfr[j] = *(const bf16x8*)((Bb) + rdB[j]);                         \
        _Pragma("unroll")                                                     \
        for (int i = 0; i < 6; i++) {                                         \
            bf16x8 af = *(const bf16x8*)((Ab) + rdA[i]);                      \
            _Pragma("unroll")                                                 \
            for (int j = 0; j < 4; j++)                                       \
                acc[i][j] = __builtin_amdgcn_mfma_f32_16x16x32_bf16(          \
                    af, bfr[j], acc[i][j], 0, 0, 0);                          \
        }                                                                     \
    }

    unsigned short *A0 = As[0], *A1 = As[1], *A2 = As[2];
    unsigned short *B0 = Bs[0], *B1 = Bs[1];

    // Prologue FIFO: A(0):3, B(0):2, A(1):3 -> outstanding 8.
    ISSUE_A(0, A0)
    ISSUE_B(0, B0)
    ISSUE_A(1, A1)

    #pragma unroll 1
    for (int kk = 0; kk < 32; ++kk) {
        asm volatile("" ::: "memory");
        if (kk == 31) __builtin_amdgcn_s_waitcnt(0x0F70);  // vmcnt(0) tail
        else          __builtin_amdgcn_s_waitcnt(0x0F73);  // vmcnt(3)
        __builtin_amdgcn_s_barrier();
        asm volatile("" ::: "memory");
        if (kk < 31) ISSUE_B(kk + 1, B1)      // B: distance-1 (~3600cy cover)
        if (kk < 30) ISSUE_A(kk + 2, A2)      // A: distance-2 (gather)
        __builtin_amdgcn_s_setprio(1);
        COMPUTE(A0, B0)
        __builtin_amdgcn_s_setprio(0);
        unsigned short* tA = A0; A0 = A1; A1 = A2; A2 = tA;
        unsigned short* tB = B0; B0 = B1; B1 = tB;
    }
#undef ISSUE_A
#undef ISSUE_B
#undef COMPUTE

    // Epilogue: C/D layout col(n)=l16, row(m)=quad*4+reg. Pad rows skipped.
    #pragma unroll
    for (int i = 0; i < 6; i++) {
        #pragma unroll
        for (int r = 0; r < 4; r++) {
            int slot = m0 + wm + i * 16 + quad * 4 + r;
            if (slot >= lim) continue;
            unsigned short* yp = y_slot + (size_t)slot * HDIM + n0;
            #pragma unroll
            for (int j = 0; j < 4; j++) {
                int col = wn + j * 16 + l16;
                yp[col] = f2b(acc[i][j][r] + be[e * HDIM + n0 + col]);
            }
        }
    }
}

// ---------------------------------------------------------------------------
// K5: combine — out[t] = g0*y[s0] + g1*y[s1]. 2 tokens per block, 16B/lane
// y_slot loads, fully coalesced; overwrites every out element.
// ---------------------------------------------------------------------------
__global__ __launch_bounds__(256) void moe_combine(
    const unsigned short* __restrict__ y_slot,
    const int* __restrict__ tok_slot, const float* __restrict__ tok_g,
    float* __restrict__ out)
{
    int tid  = threadIdx.x;
    int half = tid >> 7;              // 0/1: which token of this block
    int lane = tid & 127;             // 128 lanes x 8 bf16 = 1024 cols
    int t = blockIdx.x * 2 + half;
    int s0 = tok_slot[2 * t], s1 = tok_slot[2 * t + 1];
    float g0 = tok_g[2 * t],  g1 = tok_g[2 * t + 1];
    u16x8 a = ((const u16x8*)(y_slot + (size_t)s0 * HDIM))[lane];
    u16x8 b = ((const u16x8*)(y_slot + (size_t)s1 * HDIM))[lane];
    float4 o0, o1;
    o0.x = g0 * b2f(a[0]) + g1 * b2f(b[0]);
    o0.y = g0 * b2f(a[1]) + g1 * b2f(b[1]);
    o0.z = g0 * b2f(a[2]) + g1 * b2f(b[2]);
    o0.w = g0 * b2f(a[3]) + g1 * b2f(b[3]);
    o1.x = g0 * b2f(a[4]) + g1 * b2f(b[4]);
    o1.y = g0 * b2f(a[5]) + g1 * b2f(b[5]);
    o1.z = g0 * b2f(a[6]) + g1 * b2f(b[6]);
    o1.w = g0 * b2f(a[7]) + g1 * b2f(b[7]);
    float4* op = (float4*)(out + (size_t)t * HDIM) + lane * 2;
    op[0] = o0;
    op[1] = o1;
}

extern "C" void kernel_launch(void* const* d_in, const int* in_sizes, int n_in,
                              void* d_out, int out_size, void* d_ws, size_t ws_size,
                              hipStream_t stream) {
    const float* x  = (const float*)d_in[0];   // [B,S,D] fp32
    const float* wg = (const float*)d_in[1];   // [D,E]
    const float* we = (const float*)d_in[2];   // [E,D,H]
    const float* be = (const float*)d_in[3];   // [E,H]
    float* out = (float*)d_out;

    char* ws = (char*)d_ws;
    size_t o = 0;
    auto alloc = [&](size_t bytes) -> void* {
        void* p = ws + o;
        o = (o + bytes + 255) & ~(size_t)255;
        return p;
    };
    unsigned short* xb   = (unsigned short*)alloc((size_t)T_TOK * DDIM * 2);
    unsigned short* wtb  = (unsigned short*)alloc((size_t)NEXP * HDIM * DDIM * 2);
    unsigned short* ysl  = (unsigned short*)alloc((size_t)SLOT_CAP * HDIM * 2);
    int*   slot_token    = (int*)  alloc((size_t)SLOT_CAP * 4);
    int*   cnt_part      = (int*)  alloc((size_t)NCBLK * NEXP * 4);
    int*   counts        = (int*)  alloc(NEXP * 4);
    int*   meta          = (int*)  alloc((NEXP + 1) * 4);
    int*   tok_e         = (int*)  alloc((size_t)T_TOK * 2 * 4);
    float* tok_g         = (float*)alloc((size_t)T_TOK * 2 * 4);
    int*   tok_slot      = (int*)  alloc((size_t)T_TOK * 2 * 4);

    // 5 graph nodes (routing+wtrans fused), no memsets, no global cursor.
    moe_route_wtrans<<<4096, 256, 0, stream>>>(x, wg, we, xb, wtb, tok_e, tok_g);
    moe_count<<<NCBLK, 256, 0, stream>>>(tok_e, cnt_part);
    moe_slotfill<<<NCBLK, 256, 0, stream>>>(tok_e, cnt_part, meta, counts,
                                            slot_token, tok_slot);
    moe_gemm<<<dim3(HDIM / 128, SLOT_CAP / 192), 256, 0, stream>>>(
        xb, wtb, be, slot_token, meta, counts, ysl);
    moe_combine<<<T_TOK / 2, 256, 0, stream>>>(ysl, tok_slot, tok_g, out);
}